// Round 11
// baseline (42.434 us; speedup 1.0000x reference)
//
#include <hip/hip_runtime.h>
#include <math.h>

#define GRIDN 28
#define NPTS 784
#define BATCH 128
#define TT 25
#define KMAX 2
#define FOUT 50
#define NCLS 10
#define M0F 0.05f
#define NOFF 3025          // 55*55 relative offsets (dx,dy in [-27,27])
#define NOFFP 3032         // padded to multiple of 8 with invalid sentinels
#define D2MAX 1459         // d2 <= 2*27^2 = 1458
#define NSUB 8             // dtm sub-blocks per batch
#define PPS (NPTS / NSUB)  // 98 points per sub-block

// ---------------------------------------------------------------------------
// Compile-time offset table: all (dx,dy) sorted ascending by d2 = dx^2+dy^2,
// ties broken by lex (dx,dy) == ascending neighbor index for any fixed point
// (bit-identical visit order to the verified round-2..10 kernels).
// Packed: (d2<<12) | ((dx+27)<<6) | (dy+27). Constexpr counting sort.
// Padding entries have dx+27=63 -> always out of bounds -> wj=0 (no-op).
// ---------------------------------------------------------------------------
struct OffTab { int v[NOFFP]; };

constexpr OffTab make_offtab() {
    OffTab t{};
    int cnt[D2MAX] = {};
    for (int e = 0; e < NOFF; ++e) {
        int dx = e / 55 - 27, dy = e % 55 - 27;
        cnt[dx * dx + dy * dy]++;
    }
    int base[D2MAX] = {};
    int s = 0;
    for (int d = 0; d < D2MAX; ++d) { base[d] = s; s += cnt[d]; }
    for (int e = 0; e < NOFF; ++e) {          // ascending e => stable ties
        int dxp = e / 55, dyp = e % 55;
        int dx = dxp - 27, dy = dyp - 27;
        int d2 = dx * dx + dy * dy;
        t.v[base[d2]++] = (d2 << 12) | (dxp << 6) | dyp;
    }
    for (int e = NOFF; e < NOFFP; ++e) t.v[e] = (63 << 6) | 63;
    return t;
}
__constant__ OffTab c_off = make_offtab();

// Inter-block scratch + counters (module scope, zero-init; every launch
// returns counters to 0 at the end -> replay-deterministic, immune to the
// d_out/d_ws poison).
__device__ float        g_f[BATCH * NPTS];
__device__ float        g_x1[BATCH * FOUT];
__device__ unsigned int g_cntb[BATCH];   // per-batch dtm arrival
__device__ unsigned int g_cnt = 0;       // land arrival

// ---------------------------------------------------------------------------
// ONE kernel, 1024 blocks x 128 threads. bid = (b<<3)|sub.
// Phase 1 (all blocks): R5-verified dtm sub-scan (98 points) -> g_f via
//   agent-relaxed stores; waitcnt+barrier; fetch_add(g_cntb[b]).
// Phase 2 (last sub-block of each batch): landscape + topo-GEMM (verified
//   bodies, re-strided for 128 threads, identical per-value math) -> g_x1
//   agent-relaxed; wave-0 waitcnt; fetch_add(g_cnt).
// Phase 3 (last land block): BN (subgroup-16 tree, identical reduction
//   order) + signal + relu + head GEMM -> d_out; reset counters.
// Zero cache-maintenance ops on the whole chain (R10-validated pattern).
// d_out = [out (128x10), signal (50)].
// ---------------------------------------------------------------------------
__global__ __launch_bounds__(128) void k_all(
        const float* __restrict__ w,
        const float* __restrict__ W_topo, const float* __restrict__ b_topo,
        const float* __restrict__ gamma,  const float* __restrict__ beta,
        const float* __restrict__ W_fc,   const float* __restrict__ b_fc,
        float* __restrict__ out) {
    union SMem {
        struct { float wl[NPTS]; float red[2]; } d;                  // phase 1
        struct { float fl[NPTS]; float dl[NPTS]; float sland[TT * KMAX]; } l; // phase 2
        struct { float x1l[BATCH * FOUT]; float wfc[FOUT * NCLS]; } h;        // phase 3
    };
    __shared__ SMem sm;
    __shared__ int s_old;

    const int bid = blockIdx.x;
    const int b   = bid >> 3;
    const int sub = bid & 7;
    const int tid = threadIdx.x;

    // ---- Phase 1A: stage w (order identical to p=tid;p+=128 loop) ----
    float s = 0.f;
    #pragma unroll
    for (int k = 0; k < 6; ++k) {
        float v = w[b * NPTS + k * 128 + tid];
        sm.d.wl[k * 128 + tid] = v;
        s += v;
    }
    if (tid < NPTS - 768) {
        float v = w[b * NPTS + 768 + tid];
        sm.d.wl[768 + tid] = v;
        s += v;
    }
    for (int off = 32; off > 0; off >>= 1) s += __shfl_xor(s, off);
    if ((tid & 63) == 0) sm.d.red[tid >> 6] = s;
    __syncthreads();
    const float bound = M0F * (sm.d.red[0] + sm.d.red[1]);

    // ---- Phase 1B: chunked early-exit dtm scan (verified body) ----
    if (tid < PPS) {
        const int p = sub * PPS + tid;
        const int ix = p / GRIDN, iy = p % GRIDN;
        float cum = 0.f, acc = 0.f;
        for (int r = 0; r < NOFFP; r += 8) {
            int pk[8];
            #pragma unroll
            for (int u = 0; u < 8; ++u) pk[u] = c_off.v[r + u]; // uniform loads
            float wj[8];
            #pragma unroll
            for (int u = 0; u < 8; ++u) {                       // 8 indep LDS reads
                int jx = ix + ((pk[u] >> 6) & 63) - 27;
                int jy = iy + (pk[u] & 63) - 27;
                bool valid = ((unsigned)jx < (unsigned)GRIDN) &
                             ((unsigned)jy < (unsigned)GRIDN);
                int j = valid ? (jx * GRIDN + jy) : 0;
                wj[u] = valid ? sm.d.wl[j] : 0.f;
            }
            #pragma unroll
            for (int u = 0; u < 8; ++u) {                       // register-only
                float t = fminf(fmaxf(bound - cum, 0.f), wj[u]);
                acc += t * (float)(pk[u] >> 12);
                cum += wj[u];
            }
            if (cum >= bound) break;     // all later terms exactly 0
        }
        __hip_atomic_store(&g_f[b * NPTS + p], sqrtf(fmaxf(acc / bound, 0.f)),
                           __ATOMIC_RELAXED, __HIP_MEMORY_SCOPE_AGENT);
    }

    // ---- Phase-1 arrival: per-wave store drain, barrier, per-batch count
    asm volatile("s_waitcnt vmcnt(0)" ::: "memory");
    __syncthreads();
    if (tid == 0)
        s_old = (int)__hip_atomic_fetch_add(&g_cntb[b], 1u, __ATOMIC_RELAXED,
                                            __HIP_MEMORY_SCOPE_AGENT);
    __syncthreads();
    if (s_old != NSUB - 1) return;

    // ---- Phase 2 (last sub-block of batch b): landscape ----
    {
        float t6[6];
        #pragma unroll
        for (int k = 0; k < 6; ++k)
            t6[k] = __hip_atomic_load(&g_f[b * NPTS + k * 128 + tid],
                                      __ATOMIC_RELAXED, __HIP_MEMORY_SCOPE_AGENT);
        float tl = 0.f;
        if (tid < NPTS - 768)
            tl = __hip_atomic_load(&g_f[b * NPTS + 768 + tid],
                                   __ATOMIC_RELAXED, __HIP_MEMORY_SCOPE_AGENT);
        #pragma unroll
        for (int k = 0; k < 6; ++k) sm.l.fl[k * 128 + tid] = t6[k];
        if (tid < NPTS - 768) sm.l.fl[768 + tid] = tl;
    }
    __syncthreads();

    for (int p = tid; p < NPTS; p += 128) {
        int r = p / GRIDN, c = p % GRIDN;
        float up = sm.l.fl[(r > 0 ? r - 1 : 0) * GRIDN + c];
        float dn = sm.l.fl[(r < GRIDN - 1 ? r + 1 : GRIDN - 1) * GRIDN + c];
        float lf = sm.l.fl[r * GRIDN + (c > 0 ? c - 1 : 0)];
        float rt = sm.l.fl[r * GRIDN + (c < GRIDN - 1 ? c + 1 : GRIDN - 1)];
        sm.l.dl[p] = fmaxf(fmaxf(fmaxf(up, dn), fmaxf(lf, rt)), sm.l.fl[p]);
    }
    __syncthreads();

    const int wave = tid >> 6, lane = tid & 63;
    for (int t = wave; t < TT; t += 2) {
        float tv = (t == TT - 1) ? 2.0f : (float)t * (2.0f / (float)(TT - 1));
        float m1 = 0.f, m2 = 0.f;
        for (int p = lane; p < NPTS; p += 64) {
            float tent = fmaxf(fminf(tv - sm.l.fl[p], sm.l.dl[p] - tv), 0.f);
            if (tent > m1) { m2 = m1; m1 = tent; }
            else m2 = fmaxf(m2, tent);
        }
        for (int off = 32; off > 0; off >>= 1) {
            float o1 = __shfl_xor(m1, off), o2 = __shfl_xor(m2, off);
            float nm2 = fmaxf(fminf(m1, o1), fmaxf(m2, o2));
            m1 = fmaxf(m1, o1); m2 = nm2;
        }
        if (lane == 0) {
            sm.l.sland[2 * t]     = m1;
            sm.l.sland[2 * t + 1] = m2;
        }
    }
    __syncthreads();

    // ---- topo-GEMM (lanes 0..49 of wave 0) + land arrival ----
    if (tid < FOUT) {
        float acc = b_topo[tid];
        #pragma unroll
        for (int k = 0; k < TT * KMAX; ++k)
            acc += sm.l.sland[k] * W_topo[k * FOUT + tid];
        __hip_atomic_store(&g_x1[b * FOUT + tid], acc,
                           __ATOMIC_RELAXED, __HIP_MEMORY_SCOPE_AGENT);
    }
    if (tid == 0) {
        asm volatile("s_waitcnt vmcnt(0)" ::: "memory"); // wave 0 covers lanes 0..49
        s_old = (int)__hip_atomic_fetch_add(&g_cnt, 1u, __ATOMIC_RELAXED,
                                            __HIP_MEMORY_SCOPE_AGENT);
    }
    __syncthreads();
    if (s_old != BATCH - 1) return;

    // ---- Phase 3 (last land block): BN + signal + head ----
    for (int base = 0; base < FOUT; base += 10) {      // coalesced, 10 in flight
        float tmp[10];
        #pragma unroll
        for (int k = 0; k < 10; ++k)
            tmp[k] = __hip_atomic_load(&g_x1[(base + k) * 128 + tid],
                                       __ATOMIC_RELAXED, __HIP_MEMORY_SCOPE_AGENT);
        #pragma unroll
        for (int k = 0; k < 10; ++k)
            sm.h.x1l[(base + k) * 128 + tid] = tmp[k];
    }
    for (int e = tid; e < FOUT * NCLS; e += 128) sm.h.wfc[e] = W_fc[e];
    __syncthreads();

    for (int fbase = 0; fbase < FOUT; fbase += 8) {    // 8 features/pass
        const int f = fbase + (tid >> 4);
        const int subl = tid & 15;
        if (f < FOUT) {
            float vals[8];
            float su = 0.f, sa = 0.f;
            #pragma unroll
            for (int k = 0; k < 8; ++k) {
                float vv = sm.h.x1l[(subl + 16 * k) * FOUT + f];
                vals[k] = vv;
                su += vv;
                sa += fabsf(vv);
            }
            #pragma unroll
            for (int off = 8; off > 0; off >>= 1) {
                su += __shfl_xor(su, off);
                sa += __shfl_xor(sa, off);
            }
            const float mu = su * (1.0f / (float)BATCH);
            if (subl == 0) out[BATCH * NCLS + f] = sa;          // signal
            float dv = 0.f;
            #pragma unroll
            for (int k = 0; k < 8; ++k) {
                float d = vals[k] - mu;
                dv += d * d;
            }
            #pragma unroll
            for (int off = 8; off > 0; off >>= 1) dv += __shfl_xor(dv, off);
            const float var = dv * (1.0f / (float)BATCH);
            const float rstd = 1.0f / sqrtf(var + 1e-5f);
            const float g = gamma[f], be = beta[f];
            #pragma unroll
            for (int k = 0; k < 8; ++k) {
                float y = g * (vals[k] - mu) * rstd + be;
                sm.h.x1l[(subl + 16 * k) * FOUT + f] = fmaxf(y, 0.f);
            }
        }
    }
    __syncthreads();

    for (int idx = tid; idx < BATCH * NCLS; idx += 128) {
        const int bb = idx / NCLS, cc = idx % NCLS;
        float sacc = b_fc[cc];
        #pragma unroll
        for (int f = 0; f < FOUT; ++f)
            sacc += sm.h.x1l[bb * FOUT + f] * sm.h.wfc[f * NCLS + cc];
        out[idx] = sacc;
    }

    // ---- reset counters for the next replay (nothing races: all work done)
    __syncthreads();
    __hip_atomic_store(&g_cntb[tid], 0u, __ATOMIC_RELAXED,
                       __HIP_MEMORY_SCOPE_AGENT);          // tid 0..127 = BATCH
    if (tid == 0)
        __hip_atomic_store(&g_cnt, 0u, __ATOMIC_RELAXED,
                           __HIP_MEMORY_SCOPE_AGENT);
}

extern "C" void kernel_launch(void* const* d_in, const int* in_sizes, int n_in,
                              void* d_out, int out_size, void* d_ws, size_t ws_size,
                              hipStream_t stream) {
    const float* input  = (const float*)d_in[0];
    const float* W_topo = (const float*)d_in[1];
    const float* b_topo = (const float*)d_in[2];
    const float* gamma  = (const float*)d_in[3];
    const float* beta   = (const float*)d_in[4];
    const float* W_fc   = (const float*)d_in[5];
    const float* b_fc   = (const float*)d_in[6];
    float* out = (float*)d_out;

    k_all<<<dim3(BATCH * NSUB), dim3(128), 0, stream>>>(
        input, W_topo, b_topo, gamma, beta, W_fc, b_fc, out);
}

// Round 12
// 29.205 us; speedup vs baseline: 1.4530x; 1.4530x over previous
//
#include <hip/hip_runtime.h>
#include <math.h>

#define GRIDN 28
#define NPTS 784
#define BATCH 128
#define TT 25
#define KMAX 2
#define FOUT 50
#define NCLS 10
#define M0F 0.05f
#define NOFF 3025          // 55*55 relative offsets (dx,dy in [-27,27])
#define NOFFP 3032         // padded to multiple of 8 with invalid sentinels
#define D2MAX 1459         // d2 <= 2*27^2 = 1458
#define NSUB 8             // dtm sub-blocks per batch
#define PPS (NPTS / NSUB)  // 98 points per sub-block

// ---------------------------------------------------------------------------
// Compile-time offset table: all (dx,dy) sorted ascending by d2 = dx^2+dy^2,
// ties broken by lex (dx,dy) == ascending neighbor index for any fixed point
// (bit-identical visit order to the verified round-2..11 kernels).
// Packed: (d2<<12) | ((dx+27)<<6) | (dy+27). Constexpr counting sort.
// Padding entries have dx+27=63 -> always out of bounds -> wj=0 (no-op).
// ---------------------------------------------------------------------------
struct OffTab { int v[NOFFP]; };

constexpr OffTab make_offtab() {
    OffTab t{};
    int cnt[D2MAX] = {};
    for (int e = 0; e < NOFF; ++e) {
        int dx = e / 55 - 27, dy = e % 55 - 27;
        cnt[dx * dx + dy * dy]++;
    }
    int base[D2MAX] = {};
    int s = 0;
    for (int d = 0; d < D2MAX; ++d) { base[d] = s; s += cnt[d]; }
    for (int e = 0; e < NOFF; ++e) {          // ascending e => stable ties
        int dxp = e / 55, dyp = e % 55;
        int dx = dxp - 27, dy = dyp - 27;
        int d2 = dx * dx + dy * dy;
        t.v[base[d2]++] = (d2 << 12) | (dxp << 6) | dyp;
    }
    for (int e = NOFF; e < NOFFP; ++e) t.v[e] = (63 << 6) | 63;
    return t;
}
__constant__ OffTab c_off = make_offtab();

// Inter-kernel scratch (fully rewritten every call; deterministic).
__device__ float g_f[BATCH * NPTS];
__device__ float g_land[BATCH * TT * KMAX];
__device__ float g_y[BATCH * FOUT];

// ---------------------------------------------------------------------------
// Kernel 1: DTM scan (verified R5 body). 8 sub-blocks per batch, 1024 blocks
// x 128 thr. K1->K2 visibility via dispatch boundary; no fences.
// ---------------------------------------------------------------------------
__global__ __launch_bounds__(128) void k_dtm(const float* __restrict__ w) {
    __shared__ float wl[NPTS];
    __shared__ float red[2];
    const int b   = blockIdx.x >> 3;
    const int sub = blockIdx.x & 7;
    const int tid = threadIdx.x;

    float s = 0.f;
    for (int p = tid; p < NPTS; p += 128) {
        float v = w[b * NPTS + p];
        wl[p] = v;
        s += v;
    }
    for (int off = 32; off > 0; off >>= 1) s += __shfl_xor(s, off);
    if ((tid & 63) == 0) red[tid >> 6] = s;
    __syncthreads();
    const float bound = M0F * (red[0] + red[1]);

    if (tid < PPS) {
        const int p = sub * PPS + tid;
        const int ix = p / GRIDN, iy = p % GRIDN;
        float cum = 0.f, acc = 0.f;
        for (int r = 0; r < NOFFP; r += 8) {
            int pk[8];
            #pragma unroll
            for (int u = 0; u < 8; ++u) pk[u] = c_off.v[r + u]; // uniform loads
            float wj[8];
            #pragma unroll
            for (int u = 0; u < 8; ++u) {                       // 8 indep LDS reads
                int jx = ix + ((pk[u] >> 6) & 63) - 27;
                int jy = iy + (pk[u] & 63) - 27;
                bool valid = ((unsigned)jx < (unsigned)GRIDN) &
                             ((unsigned)jy < (unsigned)GRIDN);
                int j = valid ? (jx * GRIDN + jy) : 0;
                wj[u] = valid ? wl[j] : 0.f;
            }
            #pragma unroll
            for (int u = 0; u < 8; ++u) {                       // register-only
                float t = fminf(fmaxf(bound - cum, 0.f), wj[u]);
                acc += t * (float)(pk[u] >> 12);
                cum += wj[u];
            }
            if (cum >= bound) break;     // all later terms exactly 0
        }
        g_f[b * NPTS + p] = sqrtf(fmaxf(acc / bound, 0.f));
    }
}

// ---------------------------------------------------------------------------
// Kernel 2: landscape (verified R5 body, minus topo-GEMM). One 1024-thr
// block per batch; lane 0 of each reducing wave writes g_land directly
// (same values the verified kernels produced).
// ---------------------------------------------------------------------------
__global__ __launch_bounds__(1024) void k_land() {
    __shared__ float fl[NPTS];
    __shared__ float dl[NPTS];
    const int b = blockIdx.x;
    const int tid = threadIdx.x;

    if (tid < NPTS) fl[tid] = g_f[b * NPTS + tid];
    __syncthreads();

    if (tid < NPTS) {
        int r = tid / GRIDN, c = tid % GRIDN;
        float up = fl[(r > 0 ? r - 1 : 0) * GRIDN + c];
        float dn = fl[(r < GRIDN - 1 ? r + 1 : GRIDN - 1) * GRIDN + c];
        float lf = fl[r * GRIDN + (c > 0 ? c - 1 : 0)];
        float rt = fl[r * GRIDN + (c < GRIDN - 1 ? c + 1 : GRIDN - 1)];
        dl[tid] = fmaxf(fmaxf(fmaxf(up, dn), fmaxf(lf, rt)), fl[tid]);
    }
    __syncthreads();

    const int wave = tid >> 6, lane = tid & 63;
    for (int t = wave; t < TT; t += 16) {
        float tv = (t == TT - 1) ? 2.0f : (float)t * (2.0f / (float)(TT - 1));
        float m1 = 0.f, m2 = 0.f;
        for (int p = lane; p < NPTS; p += 64) {
            float tent = fmaxf(fminf(tv - fl[p], dl[p] - tv), 0.f);
            if (tent > m1) { m2 = m1; m1 = tent; }
            else m2 = fmaxf(m2, tent);
        }
        for (int off = 32; off > 0; off >>= 1) {
            float o1 = __shfl_xor(m1, off), o2 = __shfl_xor(m2, off);
            float nm2 = fmaxf(fminf(m1, o1), fmaxf(m2, o2));
            m1 = fmaxf(m1, o1); m2 = nm2;
        }
        if (lane == 0) {
            g_land[b * (TT * KMAX) + 2 * t]     = m1;
            g_land[b * (TT * KMAX) + 2 * t + 1] = m2;
        }
    }
}

// ---------------------------------------------------------------------------
// Kernel 3: head part 1 (verified R3 body). One block per output feature ff
// (50 blocks, 128 thr, thread = batch row). x1 = land@W_topo + b_topo;
// signal = sum|x1|; two-pass batchnorm stats via shuffle trees; g_y=relu(y).
// ---------------------------------------------------------------------------
__global__ __launch_bounds__(128) void k_head1(
        const float* __restrict__ W_topo, const float* __restrict__ b_topo,
        const float* __restrict__ gamma,  const float* __restrict__ beta,
        float* __restrict__ out) {
    __shared__ float ld[BATCH * TT * KMAX];
    __shared__ float wt[TT * KMAX];
    __shared__ float r0[2], r1[2], r2[2];
    const int ff = blockIdx.x;
    const int bb = threadIdx.x;

    for (int e = bb; e < BATCH * TT * KMAX; e += 128) ld[e] = g_land[e];
    if (bb < TT * KMAX) wt[bb] = W_topo[bb * FOUT + ff];
    __syncthreads();

    float s = b_topo[ff];
    #pragma unroll
    for (int k = 0; k < TT * KMAX; ++k) s += ld[bb * (TT * KMAX) + k] * wt[k];

    float su = s, sa = fabsf(s);
    for (int off = 32; off > 0; off >>= 1) {
        su += __shfl_xor(su, off);
        sa += __shfl_xor(sa, off);
    }
    if ((bb & 63) == 0) { r0[bb >> 6] = su; r1[bb >> 6] = sa; }
    __syncthreads();
    const float mu = (r0[0] + r0[1]) / (float)BATCH;
    if (bb == 0) out[BATCH * NCLS + ff] = r1[0] + r1[1];   // signal

    float d = s - mu, dv = d * d;
    for (int off = 32; off > 0; off >>= 1) dv += __shfl_xor(dv, off);
    if ((bb & 63) == 0) r2[bb >> 6] = dv;
    __syncthreads();
    const float var = (r2[0] + r2[1]) / (float)BATCH;

    float y = gamma[ff] * d * (1.0f / sqrtf(var + 1e-5f)) + beta[ff];
    g_y[bb * FOUT + ff] = fmaxf(y, 0.f);
}

// ---------------------------------------------------------------------------
// Kernel 4: head part 2 (verified R3 body). out = relu_y @ W_fc + b_fc.
// ---------------------------------------------------------------------------
__global__ __launch_bounds__(256) void k_head2(
        const float* __restrict__ W_fc, const float* __restrict__ b_fc,
        float* __restrict__ out) {
    __shared__ float wfc[FOUT * NCLS];
    for (int e = threadIdx.x; e < FOUT * NCLS; e += 256) wfc[e] = W_fc[e];
    __syncthreads();
    const int tid = blockIdx.x * 256 + threadIdx.x;
    if (tid < BATCH * NCLS) {
        int bb = tid / NCLS, cc = tid % NCLS;
        float s = b_fc[cc];
        #pragma unroll
        for (int f = 0; f < FOUT; ++f)
            s += g_y[bb * FOUT + f] * wfc[f * NCLS + cc];
        out[tid] = s;
    }
}

extern "C" void kernel_launch(void* const* d_in, const int* in_sizes, int n_in,
                              void* d_out, int out_size, void* d_ws, size_t ws_size,
                              hipStream_t stream) {
    const float* input  = (const float*)d_in[0];
    const float* W_topo = (const float*)d_in[1];
    const float* b_topo = (const float*)d_in[2];
    const float* gamma  = (const float*)d_in[3];
    const float* beta   = (const float*)d_in[4];
    const float* W_fc   = (const float*)d_in[5];
    const float* b_fc   = (const float*)d_in[6];
    float* out = (float*)d_out;

    k_dtm  <<<dim3(BATCH * NSUB), dim3(128), 0, stream>>>(input);
    k_land <<<dim3(BATCH), dim3(1024), 0, stream>>>();
    k_head1<<<dim3(FOUT), dim3(128), 0, stream>>>(W_topo, b_topo, gamma, beta, out);
    k_head2<<<dim3((BATCH * NCLS + 255) / 256), dim3(256), 0, stream>>>(W_fc, b_fc, out);
}

// Round 13
// 28.771 us; speedup vs baseline: 1.4749x; 1.0151x over previous
//
#include <hip/hip_runtime.h>
#include <math.h>

#define GRIDN 28
#define NPTS 784
#define BATCH 128
#define TT 25
#define KMAX 2
#define FOUT 50
#define NCLS 10
#define M0F 0.05f
#define NOFF 3025          // 55*55 relative offsets (dx,dy in [-27,27])
#define NOFFP 3032         // padded to multiple of 8 with invalid sentinels
#define D2MAX 1459         // d2 <= 2*27^2 = 1458
#define NSUB 8             // dtm sub-blocks per batch
#define PPS (NPTS / NSUB)  // 98 points per sub-block

// ---------------------------------------------------------------------------
// Compile-time offset table: all (dx,dy) sorted ascending by d2 = dx^2+dy^2,
// ties broken by lex (dx,dy) == ascending neighbor index for any fixed point
// (bit-identical visit order to the verified round-2..12 kernels).
// Packed: (d2<<12) | ((dx+27)<<6) | (dy+27). Constexpr counting sort.
// Padding entries have dx+27=63 -> always out of bounds -> wj=0 (no-op).
// ---------------------------------------------------------------------------
struct OffTab { int v[NOFFP]; };

constexpr OffTab make_offtab() {
    OffTab t{};
    int cnt[D2MAX] = {};
    for (int e = 0; e < NOFF; ++e) {
        int dx = e / 55 - 27, dy = e % 55 - 27;
        cnt[dx * dx + dy * dy]++;
    }
    int base[D2MAX] = {};
    int s = 0;
    for (int d = 0; d < D2MAX; ++d) { base[d] = s; s += cnt[d]; }
    for (int e = 0; e < NOFF; ++e) {          // ascending e => stable ties
        int dxp = e / 55, dyp = e % 55;
        int dx = dxp - 27, dy = dyp - 27;
        int d2 = dx * dx + dy * dy;
        t.v[base[d2]++] = (d2 << 12) | (dxp << 6) | dyp;
    }
    for (int e = NOFF; e < NOFFP; ++e) t.v[e] = (63 << 6) | 63;
    return t;
}
__constant__ OffTab c_off = make_offtab();

// Inter-kernel scratch (fully rewritten every call; deterministic).
__device__ float g_f[BATCH * NPTS];
__device__ float g_x1[BATCH * FOUT];

// ---------------------------------------------------------------------------
// Kernel 1: DTM scan, 8 sub-blocks per batch (1024 blocks x 128 thr -> full
// GPU, ~4 blocks/CU). Each sub-block stages w in LDS, recomputes bound with
// a fixed reduction shape (identical across sub-blocks), scans its 98 points
// with the 8-wide chunked early-exit loop (offsets from __constant__ via
// uniform scalar loads; term = min(max(bound-cum,0), wj), wj=0 for OOB).
// ---------------------------------------------------------------------------
__global__ __launch_bounds__(128) void k_dtm(const float* __restrict__ w) {
    __shared__ float wl[NPTS];
    __shared__ float red[2];
    const int b   = blockIdx.x >> 3;
    const int sub = blockIdx.x & 7;
    const int tid = threadIdx.x;

    float s = 0.f;
    for (int p = tid; p < NPTS; p += 128) {
        float v = w[b * NPTS + p];
        wl[p] = v;
        s += v;
    }
    for (int off = 32; off > 0; off >>= 1) s += __shfl_xor(s, off);
    if ((tid & 63) == 0) red[tid >> 6] = s;
    __syncthreads();
    const float bound = M0F * (red[0] + red[1]);

    if (tid < PPS) {
        const int p = sub * PPS + tid;
        const int ix = p / GRIDN, iy = p % GRIDN;
        float cum = 0.f, acc = 0.f;
        for (int r = 0; r < NOFFP; r += 8) {
            int pk[8];
            #pragma unroll
            for (int u = 0; u < 8; ++u) pk[u] = c_off.v[r + u]; // scalar loads
            float wj[8];
            #pragma unroll
            for (int u = 0; u < 8; ++u) {                       // 8 indep LDS reads
                int jx = ix + ((pk[u] >> 6) & 63) - 27;
                int jy = iy + (pk[u] & 63) - 27;
                bool valid = ((unsigned)jx < (unsigned)GRIDN) &
                             ((unsigned)jy < (unsigned)GRIDN);
                int j = valid ? (jx * GRIDN + jy) : 0;
                wj[u] = valid ? wl[j] : 0.f;
            }
            #pragma unroll
            for (int u = 0; u < 8; ++u) {                       // register-only
                float t = fminf(fmaxf(bound - cum, 0.f), wj[u]);
                acc += t * (float)(pk[u] >> 12);
                cum += wj[u];
            }
            if (cum >= bound) break;     // all later terms exactly 0
        }
        g_f[b * NPTS + p] = sqrtf(fmaxf(acc / bound, 0.f));
    }
}

// ---------------------------------------------------------------------------
// Kernel 2: landscape + topo-GEMM. One 1024-thr block per batch.
// Phase C: 5-point neighborhood max.
// Phase D: 25 tents, per-wave top-2 -> sland[50] (LDS).
// Phase E: x1[b][:] = sland @ W_topo + b_topo -> g_x1.
// ---------------------------------------------------------------------------
__global__ __launch_bounds__(1024) void k_land(
        const float* __restrict__ W_topo, const float* __restrict__ b_topo) {
    __shared__ float fl[NPTS];
    __shared__ float dl[NPTS];
    __shared__ float sland[TT * KMAX];
    const int b = blockIdx.x;
    const int tid = threadIdx.x;

    if (tid < NPTS) fl[tid] = g_f[b * NPTS + tid];
    __syncthreads();

    if (tid < NPTS) {
        int r = tid / GRIDN, c = tid % GRIDN;
        float up = fl[(r > 0 ? r - 1 : 0) * GRIDN + c];
        float dn = fl[(r < GRIDN - 1 ? r + 1 : GRIDN - 1) * GRIDN + c];
        float lf = fl[r * GRIDN + (c > 0 ? c - 1 : 0)];
        float rt = fl[r * GRIDN + (c < GRIDN - 1 ? c + 1 : GRIDN - 1)];
        dl[tid] = fmaxf(fmaxf(fmaxf(up, dn), fmaxf(lf, rt)), fl[tid]);
    }
    __syncthreads();

    const int wave = tid >> 6, lane = tid & 63;
    for (int t = wave; t < TT; t += 16) {
        float tv = (t == TT - 1) ? 2.0f : (float)t * (2.0f / (float)(TT - 1));
        float m1 = 0.f, m2 = 0.f;
        for (int p = lane; p < NPTS; p += 64) {
            float tent = fmaxf(fminf(tv - fl[p], dl[p] - tv), 0.f);
            if (tent > m1) { m2 = m1; m1 = tent; }
            else m2 = fmaxf(m2, tent);
        }
        for (int off = 32; off > 0; off >>= 1) {
            float o1 = __shfl_xor(m1, off), o2 = __shfl_xor(m2, off);
            float nm2 = fmaxf(fminf(m1, o1), fmaxf(m2, o2));
            m1 = fmaxf(m1, o1); m2 = nm2;
        }
        if (lane == 0) {
            sland[2 * t]     = m1;
            sland[2 * t + 1] = m2;
        }
    }
    __syncthreads();

    if (tid < FOUT) {
        float acc = b_topo[tid];
        #pragma unroll
        for (int k = 0; k < TT * KMAX; ++k)
            acc += sland[k] * W_topo[k * FOUT + tid];
        g_x1[b * FOUT + tid] = acc;
    }
}

// ---------------------------------------------------------------------------
// Kernel 3: batchnorm + head, one 1024-thr block.
// Stats per feature via 16-lane shuffle groups (f = tid>>4, sub = tid&15,
// each sub owns 8 batch rows kept in registers for the two-pass var).
// signal = sum_b |x1|; relu(y) written back to LDS; out = relu_y @ W_fc + b_fc.
// d_out = [out (128x10), signal (50)].
// ---------------------------------------------------------------------------
__global__ __launch_bounds__(1024) void k_bnhead(
        const float* __restrict__ gamma, const float* __restrict__ beta,
        const float* __restrict__ W_fc,  const float* __restrict__ b_fc,
        float* __restrict__ out) {
    __shared__ float x1l[BATCH * FOUT];
    __shared__ float wfc[FOUT * NCLS];
    const int tid = threadIdx.x;

    for (int e = tid; e < BATCH * FOUT; e += 1024) x1l[e] = g_x1[e];
    if (tid < FOUT * NCLS) wfc[tid] = W_fc[tid];
    __syncthreads();

    if (tid < FOUT * 16) {
        const int f = tid >> 4, sub = tid & 15;
        float vals[8];
        float su = 0.f, sa = 0.f;
        #pragma unroll
        for (int k = 0; k < 8; ++k) {
            float v = x1l[(sub + 16 * k) * FOUT + f];
            vals[k] = v;
            su += v;
            sa += fabsf(v);
        }
        #pragma unroll
        for (int off = 8; off > 0; off >>= 1) {
            su += __shfl_xor(su, off);
            sa += __shfl_xor(sa, off);
        }
        const float mu = su * (1.0f / (float)BATCH);
        if (sub == 0) out[BATCH * NCLS + f] = sa;          // signal
        float dv = 0.f;
        #pragma unroll
        for (int k = 0; k < 8; ++k) {
            float d = vals[k] - mu;
            dv += d * d;
        }
        #pragma unroll
        for (int off = 8; off > 0; off >>= 1) dv += __shfl_xor(dv, off);
        const float var = dv * (1.0f / (float)BATCH);
        const float rstd = 1.0f / sqrtf(var + 1e-5f);
        const float g = gamma[f], be = beta[f];
        #pragma unroll
        for (int k = 0; k < 8; ++k) {
            float y = g * (vals[k] - mu) * rstd + be;
            x1l[(sub + 16 * k) * FOUT + f] = fmaxf(y, 0.f);
        }
    }
    __syncthreads();

    for (int idx = tid; idx < BATCH * NCLS; idx += 1024) {
        const int bb = idx / NCLS, cc = idx % NCLS;
        float s = b_fc[cc];
        #pragma unroll
        for (int f = 0; f < FOUT; ++f)
            s += x1l[bb * FOUT + f] * wfc[f * NCLS + cc];
        out[idx] = s;
    }
}

extern "C" void kernel_launch(void* const* d_in, const int* in_sizes, int n_in,
                              void* d_out, int out_size, void* d_ws, size_t ws_size,
                              hipStream_t stream) {
    const float* input  = (const float*)d_in[0];
    const float* W_topo = (const float*)d_in[1];
    const float* b_topo = (const float*)d_in[2];
    const float* gamma  = (const float*)d_in[3];
    const float* beta   = (const float*)d_in[4];
    const float* W_fc   = (const float*)d_in[5];
    const float* b_fc   = (const float*)d_in[6];
    float* out = (float*)d_out;

    k_dtm   <<<dim3(BATCH * NSUB), dim3(128), 0, stream>>>(input);
    k_land  <<<dim3(BATCH), dim3(1024), 0, stream>>>(W_topo, b_topo);
    k_bnhead<<<dim3(1), dim3(1024), 0, stream>>>(gamma, beta, W_fc, b_fc, out);
}